// Round 12
// baseline (107.629 us; speedup 1.0000x reference)
//
#include <hip/hip_runtime.h>
#include <math.h>

// Ising-flip, round 12: SINGLE fused kernel. sc is computed on the fly from
// the s-loads the flip already needs (3-row rolling register file), shared
// across columns via an 8-row LDS ring (one barrier/step). Eliminates the
// separate sc pass (128MB read + 32MB ws round-trip + serialization).
// Numerics identical to all passing rounds (absmax 0.0):
//   sc: sequential channel sum c=0..7
//   Js: center, y-1, y+1, x-1, x+1, y-2, y+2, x-2, x+2 (left-assoc adds)
//   de=(2s)*Js ; arg=(-de)*b ; __expf band decide, else exact double exp.

#define NB 4
#define NC 8
#define HH 1024
#define WW 1024
#define PIX (HH * WW)
#define S 8
#define NBLK (NB * (HH / S))            // 512 blocks, %8==0 -> bijective swizzle

typedef float f32x4 __attribute__((ext_vector_type(4)));

__global__ __launch_bounds__(256) void ising_fused(const float* __restrict__ x,
                                                   const float* __restrict__ rnd,
                                                   const float* __restrict__ dr,
                                                   float* __restrict__ out) {
    __shared__ float scb[8][WW];        // 32 KB ring: sc rows (row & 7)

    int bid     = blockIdx.x;
    int logical = (bid & 7) * (NBLK / 8) + (bid >> 3);   // XCD-contiguous strips
    int n       = logical / (HH / S);
    int y0      = (logical % (HH / S)) * S;
    int xc      = (int)(threadIdx.x << 2);               // 256 thr * 4 px = row
    int xA      = (xc - 4) & (WW - 1);
    int xC      = (xc + 4) & (WW - 1);

    const float* xn = x   + (size_t)n * 9  * PIX;
    const float* rn = rnd + (size_t)n * NC * PIX;
    float*       on = out + (size_t)n * 9  * PIX;

    f32x4 svA[NC], svB[NC], svC[NC];    // s rows y, y+1, y+2 (static idx only)

    // ---- prologue: sc rows y0-2, y0-1 (halo, s discarded), y0->svA, y0+1->svB
#pragma unroll
    for (int h = 0; h < 2; ++h) {
        int yr = (y0 - 2 + h) & (HH - 1);
        const float* base = xn + ((size_t)yr << 10) + xc;
        f32x4 s = *reinterpret_cast<const f32x4*>(base);
#pragma unroll
        for (int c = 1; c < NC; ++c)
            s = s + *reinterpret_cast<const f32x4*>(base + (size_t)c * PIX);
        *reinterpret_cast<f32x4*>(&scb[(y0 - 2 + h) & 7][xc]) = s;
    }
    {
        const float* base = xn + ((size_t)y0 << 10) + xc;
#pragma unroll
        for (int c = 0; c < NC; ++c)
            svA[c] = *reinterpret_cast<const f32x4*>(base + (size_t)c * PIX);
        f32x4 s = svA[0];
#pragma unroll
        for (int c = 1; c < NC; ++c) s = s + svA[c];
        *reinterpret_cast<f32x4*>(&scb[y0 & 7][xc]) = s;
    }
    {
        int yr = (y0 + 1) & (HH - 1);
        const float* base = xn + ((size_t)yr << 10) + xc;
#pragma unroll
        for (int c = 0; c < NC; ++c)
            svB[c] = *reinterpret_cast<const f32x4*>(base + (size_t)c * PIX);
        f32x4 s = svB[0];
#pragma unroll
        for (int c = 1; c < NC; ++c) s = s + svB[c];
        *reinterpret_cast<f32x4*>(&scb[(y0 + 1) & 7][xc]) = s;
    }
    // first loop iteration's barrier covers these writes

#pragma unroll
    for (int st = 0; st < S; ++st) {
        int y  = y0 + st;
        int yw = y & (HH - 1);

        // load s row y+2, compute its sc quad, publish to LDS ring
        {
            int yr = (y + 2) & (HH - 1);
            const float* base = xn + ((size_t)yr << 10) + xc;
#pragma unroll
            for (int c = 0; c < NC; ++c)
                svC[c] = *reinterpret_cast<const f32x4*>(base + (size_t)c * PIX);
            f32x4 s = svC[0];
#pragma unroll
            for (int c = 1; c < NC; ++c) s = s + svC[c];
            *reinterpret_cast<f32x4*>(&scb[(y + 2) & 7][xc]) = s;
        }
        f32x4 bv = __builtin_nontemporal_load(reinterpret_cast<const f32x4*>(
                       xn + (size_t)NC * PIX + ((size_t)yw << 10) + xc));
        f32x4 dv = *reinterpret_cast<const f32x4*>(dr + ((size_t)yw << 10) + xc);

        __syncthreads();                 // sc(y+2) visible; ring dist 5<8 safe

        f32x4 m2  = *reinterpret_cast<const f32x4*>(&scb[(y - 2) & 7][xc]);
        f32x4 m1  = *reinterpret_cast<const f32x4*>(&scb[(y - 1) & 7][xc]);
        f32x4 ce  = *reinterpret_cast<const f32x4*>(&scb[ y      & 7][xc]);
        f32x4 p1  = *reinterpret_cast<const f32x4*>(&scb[(y + 1) & 7][xc]);
        f32x4 p2  = *reinterpret_cast<const f32x4*>(&scb[(y + 2) & 7][xc]);
        f32x4 rAq = *reinterpret_cast<const f32x4*>(&scb[ y      & 7][xA]);
        f32x4 rCq = *reinterpret_cast<const f32x4*>(&scb[ y      & 7][xC]);

        // Js per pixel, exact reference add order
        float Js[4];
#pragma unroll
        for (int i = 0; i < 4; ++i) {
            float vx1m = (i == 0) ? rAq[3] : ce[i - 1];
            float vx1p = (i == 3) ? rCq[0] : ce[i + 1];
            float vx2m = (i < 2) ? rAq[2 + i] : ce[i - 2];
            float vx2p = (i < 2) ? ce[i + 2] : rCq[i - 2];
            float j = ce[i];
            j = j + m1[i]; j = j + p1[i];
            j = j + vx1m;  j = j + vx1p;
            j = j + m2[i]; j = j + p2[i];
            j = j + vx2m;  j = j + vx2p;
            Js[i] = j;
        }
        bool dm[4];
#pragma unroll
        for (int i = 0; i < 4; ++i) dm[i] = dv[i] > 0.5f;

        const float* rbase = rn + ((size_t)yw << 10) + xc;
        float*       obase = on + ((size_t)yw << 10) + xc;

#pragma unroll
        for (int c = 0; c < NC; ++c) {
            f32x4 sv = svA[c];
            f32x4 rv = __builtin_nontemporal_load(
                           reinterpret_cast<const f32x4*>(rbase + (size_t)c * PIX));
            float de[4], arg[4];
            bool fl[4], und[4];
            bool anyund = false;
#pragma unroll
            for (int i = 0; i < 4; ++i) {
                de[i]  = (2.0f * sv[i]) * Js[i];
                arg[i] = (-de[i]) * bv[i];
                float pa   = __expf(arg[i]);       // rel err <~6e-6
                float band = pa * 4.0e-5f;         // ~7x margin
                bool  l = rv[i] < pa - band;
                bool  h = rv[i] > pa + band;
                fl[i]  = l;
                und[i] = (de[i] > 0.0f) && !l && !h;
                anyund = anyund || und[i];
            }
            f32x4 o;
            if (__any(anyund)) {                   // rare exact path
#pragma unroll
                for (int i = 0; i < 4; ++i) {
                    bool take;
                    if (de[i] <= 0.0f)  take = true;
                    else if (und[i])    take = rv[i] < (float)exp((double)arg[i]);
                    else                take = fl[i];
                    o[i] = (take && dm[i]) ? -sv[i] : sv[i];
                }
            } else {
#pragma unroll
                for (int i = 0; i < 4; ++i) {
                    bool take = (de[i] <= 0.0f) || fl[i];
                    o[i] = (take && dm[i]) ? -sv[i] : sv[i];
                }
            }
            __builtin_nontemporal_store(
                o, reinterpret_cast<f32x4*>(obase + (size_t)c * PIX));
        }
        __builtin_nontemporal_store(
            bv, reinterpret_cast<f32x4*>(obase + (size_t)NC * PIX));

        // rotate the 3-row register file (unrolled -> pure SSA renaming)
#pragma unroll
        for (int c = 0; c < NC; ++c) { svA[c] = svB[c]; svB[c] = svC[c]; }
    }
}

extern "C" void kernel_launch(void* const* d_in, const int* in_sizes, int n_in,
                              void* d_out, int out_size, void* d_ws, size_t ws_size,
                              hipStream_t stream) {
    const float* x   = (const float*)d_in[0];
    const float* rnd = (const float*)d_in[1];
    const float* dr  = (const float*)d_in[2];
    float* out = (float*)d_out;
    (void)d_ws; (void)ws_size;

    ising_fused<<<NBLK, 256, 0, stream>>>(x, rnd, dr, out);
}